// Round 11
// baseline (146.726 us; speedup 1.0000x reference)
//
#include <hip/hip_runtime.h>
#include <math.h>

// Problem constants
#define BS    2048            // batch
#define NROW  4096            // B*V = N
#define EDIM  256
#define INVT  (1.0f/0.07f)

typedef float  float4v __attribute__((ext_vector_type(4)));
typedef short  short8v __attribute__((ext_vector_type(8)));

static __device__ __forceinline__ unsigned short f2bf(float x) {
    // round-to-nearest-even f32 -> bf16 (inputs are finite)
    unsigned u = __builtin_bit_cast(unsigned, x);
    u += 0x7fffu + ((u >> 16) & 1u);
    return (unsigned short)(u >> 16);
}

// ---------------- prep kernel: normalize + label bits + zero accumulators ----
__global__ void prep_kernel(const float* __restrict__ feat, const float* __restrict__ labels,
                            unsigned short* __restrict__ fnb, unsigned* __restrict__ bits,
                            float* __restrict__ zacc) {
    const int b = blockIdx.x, t = threadIdx.x;
    if (b < NROW) {
        int bb = b & (BS - 1);
        int v = b >> 11;
        float x = feat[(size_t)bb * (2 * EDIM) + (size_t)v * EDIM + t];
        float ss = x * x;
#pragma unroll
        for (int off = 32; off > 0; off >>= 1)
            ss += __shfl_xor(ss, off, 64);
        float nrm = fmaxf(sqrtf(ss), 1e-12f);
        fnb[(size_t)b * EDIM + t] = f2bf(x / nrm);
    } else {
        int g = (b - NROW) * 256 + t;   // 0..2047
        unsigned bb = 0;
#pragma unroll
        for (int d = 0; d < 10; ++d)
            bb |= (labels[g * 10 + d] != 0.0f ? 1u : 0u) << d;
        bits[g] = bb;
        // zero S (N*4), Num (N), Cnt (N*4), red[2], done[1] = N*9+3 words
        for (int k = g; k < NROW * 9 + 3; k += 2048) zacc[k] = 0.0f;
    }
}

// ---------------- main kernel: barrier-free reg-direct, FULL residency -------
// r10 post-mortem: barrier-free reg-direct was clean (no spill, 0 conflicts,
// FETCH/WRITE minimal) but STARVED -- 512 blocks = 2 waves/SIMD, VALUBusy
// 19.5% = L2 latency uncovered.  Its 64-reg BF double-buffer forced (256,3)
// and the half-grid.  This round halves the B footprint so the same physics
// fits (256,4) at grid (64,16) = 1024 blocks = 4 blocks/CU, 16 waves/CU,
// single round, zero tail -- 2x r10's TLP.
// SELF-OVERWRITING single BF (32 regs): per (js,h) phase the 2 MFMAs consume
// bf.v[h], then the next instructions refill bf.v[h] with (js+1,h) data.
// WAR safe: MFMA reads operands at issue; loads issued after in program
// order.  Prefetch distance = one full js iteration (4 h-phases + ~240cy
// epilogue ~= 500-700cy) >> L2 latency (~200cy); 8 loads always in flight.
// Budget: af32 + bf32 + dacc16 + Sp16 + np/cpk/ibr 12 + addr ~12 ~= 120 <= 128.
// Spill tripwire: FETCH > 11MB or WRITE > 15MB => revert to r6 verbatim.
// js=15 refill reads 8KB past fnb into the S region: in-workspace, never
// consumed, harmless.  No LDS, no __syncthreads, no fences (r1-r4 lessons).
// B-frag layout == A-frag layout == row-major fnb row (lane -> n=lane&15,
// k=quad*8+e per 32-wide kk chunk).
// C/D layout (m89/m91): col = lane&15 (j), row = (lane>>4)*4 + reg (i).
__global__ __launch_bounds__(256, 4) void main_kernel(
    const unsigned short* __restrict__ fnb, const unsigned* __restrict__ bits,
    float* __restrict__ S, float* __restrict__ Num, float* __restrict__ Cnt) {

    const int tid  = threadIdx.x;
    const int lane = tid & 63;
    const int wave = tid >> 6;
    const int quad = lane >> 4;
    const int ml   = lane & 15;
    const int i0   = blockIdx.x * 64 + wave * 16;
    const int jc0  = blockIdx.y * 256;

    // A fragments: af[h][kk], 8 x short8 = 32 VGPRs (rows i0..i0+15)
    short8v af[4][2];
    {
        const unsigned short* ap = fnb + (size_t)(i0 + ml) * EDIM + quad * 8;
#pragma unroll
        for (int h = 0; h < 4; ++h)
#pragma unroll
            for (int kk = 0; kk < 2; ++kk)
                af[h][kk] = *(const short8v*)(ap + h * 64 + kk * 32);
    }

    unsigned ibr[4];
#pragma unroll
    for (int r = 0; r < 4; ++r)
        ibr[r] = bits[(i0 + quad * 4 + r) & (BS - 1)];

    float    Sp[4][4] = {};
    float    np[4] = {};
    unsigned cpk[4] = {};   // per row: 4 x 8-bit argmax-head counts (<=16 each)

    // single self-overwriting B fragment buffer (32 VGPR)
    short8v bfv[4][2];
    const unsigned short* bp = fnb + (size_t)(jc0 + ml) * EDIM + quad * 8;  // js=0
#pragma unroll
    for (int h = 0; h < 4; ++h)
#pragma unroll
        for (int kk = 0; kk < 2; ++kk)
            bfv[h][kk] = *(const short8v*)(bp + h * 64 + kk * 32);

    for (int js = 0; js < 16; ++js) {
        const unsigned short* bpn = bp + 16 * EDIM;   // next js's 16 rows
        const int j0 = jc0 + js * 16;
        const unsigned jb = bits[(j0 + ml) & (BS - 1)];

        float4v dacc[4];
#pragma unroll
        for (int h = 0; h < 4; ++h) dacc[h] = (float4v){0.f, 0.f, 0.f, 0.f};

        // consume bf.v[h], then immediately refill it for js+1 (WAR-safe)
#pragma unroll
        for (int h = 0; h < 4; ++h) {
            dacc[h] = __builtin_amdgcn_mfma_f32_16x16x32_bf16(af[h][0], bfv[h][0], dacc[h], 0, 0, 0);
            dacc[h] = __builtin_amdgcn_mfma_f32_16x16x32_bf16(af[h][1], bfv[h][1], dacc[h], 0, 0, 0);
            bfv[h][0] = *(const short8v*)(bpn + h * 64);
            bfv[h][1] = *(const short8v*)(bpn + h * 64 + 32);
        }

        const int j = j0 + ml;
#pragma unroll
        for (int r = 0; r < 4; ++r) {
            const int i = i0 + quad * 4 + r;
            const float d0 = dacc[0][r];
            const float d1 = dacc[1][r];
            const float d2 = dacc[2][r];
            const float d3 = dacc[3][r];
            // argmax, first index wins ties
            float bd = d0; int bh = 0;
            if (d1 > bd) { bd = d1; bh = 1; }
            if (d2 > bd) { bd = d2; bh = 2; }
            if (d3 > bd) { bd = d3; bh = 3; }
            const bool off = (i != j);
            const float e0 = __expf(fmaf(d0, INVT, -INVT));
            const float e1 = __expf(fmaf(d1, INVT, -INVT));
            const float e2 = __expf(fmaf(d2, INVT, -INVT));
            const float e3 = __expf(fmaf(d3, INVT, -INVT));
            if (off) {
                Sp[r][0] += e0; Sp[r][1] += e1; Sp[r][2] += e2; Sp[r][3] += e3;
            }
            if (off && (ibr[r] & jb)) {
                np[r] += bd;              // raw dot; * INVT at flush
                cpk[r] += 1u << (bh * 8);
            }
        }
        bp = bpn;
    }

    // reduce the 16 lanes sharing each row, then one global atomic per value
#pragma unroll
    for (int r = 0; r < 4; ++r) {
        const int i = i0 + quad * 4 + r;
        float v[9];
        v[0] = np[r];
#pragma unroll
        for (int h = 0; h < 4; ++h) v[1 + h] = Sp[r][h];
#pragma unroll
        for (int h = 0; h < 4; ++h) v[5 + h] = (float)((cpk[r] >> (8 * h)) & 255u);
#pragma unroll
        for (int k = 0; k < 9; ++k) {
            float x = v[k];
            x += __shfl_xor(x, 1, 64);
            x += __shfl_xor(x, 2, 64);
            x += __shfl_xor(x, 4, 64);
            x += __shfl_xor(x, 8, 64);
            v[k] = x;
        }
        if (ml == 0) {
            atomicAdd(&Num[i], v[0] * INVT);
#pragma unroll
            for (int h = 0; h < 4; ++h) atomicAdd(&S[i * 4 + h], v[1 + h]);
#pragma unroll
            for (int h = 0; h < 4; ++h) atomicAdd(&Cnt[i * 4 + h], v[5 + h]);
        }
    }
}

// ---------------- final reduction: 16 blocks, last block writes out --------
__global__ void final_kernel(const float* __restrict__ S, const float* __restrict__ Num,
                             const float* __restrict__ Cnt, float* __restrict__ red,
                             unsigned* __restrict__ done, float* __restrict__ out) {
    const int tid = threadIdx.x;
    const int i = blockIdx.x * 256 + tid;   // grid 16 x 256 = 4096 rows exactly
    float c = 0.f;
    float numr = Num[i];
#pragma unroll
    for (int h = 0; h < 4; ++h) {
        float sh = S[i * 4 + h];
        float ch = Cnt[i * 4 + h];
        numr -= ch * (INVT + logf(sh));
        c += ch;
    }
    float ls = 0.f, lc = 0.f;
    if (c > 0.f) { ls = -(numr / c); lc = 1.f; }

    __shared__ float rs[256], rc[256];
    rs[tid] = ls; rc[tid] = lc;
    __syncthreads();
    for (int s = 128; s > 0; s >>= 1) {
        if (tid < s) { rs[tid] += rs[tid + s]; rc[tid] += rc[tid + s]; }
        __syncthreads();
    }
    if (tid == 0) {
        atomicAdd(&red[0], rs[0]);
        atomicAdd(&red[1], rc[0]);
        __threadfence();
        if (atomicAdd(done, 1u) == 15u) {
            float s = atomicAdd(&red[0], 0.0f);
            float cc = atomicAdd(&red[1], 0.0f);
            out[0] = s / cc;
        }
    }
}

extern "C" void kernel_launch(void* const* d_in, const int* in_sizes, int n_in,
                              void* d_out, int out_size, void* d_ws, size_t ws_size,
                              hipStream_t stream) {
    const float* feat = (const float*)d_in[0];    // (2048, 2, 256) f32
    const float* labels = (const float*)d_in[1];  // (2048, 10) f32
    float* out = (float*)d_out;

    char* ws = (char*)d_ws;
    unsigned short* fnb = (unsigned short*)ws;                     // N*E bf16 (2 MB)
    float* S = (float*)(ws + (size_t)NROW * EDIM * sizeof(unsigned short));
    float* Num = S + NROW * 4;
    float* Cnt = Num + NROW;
    float* red = Cnt + NROW * 4;              // red[0]=sum, red[1]=count
    unsigned* done = (unsigned*)(red + 2);    // completion counter
    unsigned* bits = done + 1;                // BS label bitmasks

    prep_kernel<<<NROW + 8, 256, 0, stream>>>(feat, labels, fnb, bits, S);
    main_kernel<<<dim3(64, 16), 256, 0, stream>>>(fnb, bits, S, Num, Cnt);
    final_kernel<<<16, 256, 0, stream>>>(S, Num, Cnt, red, done, out);
}

// Round 12
// 108.093 us; speedup vs baseline: 1.3574x; 1.3574x over previous
//
#include <hip/hip_runtime.h>
#include <math.h>

// Problem constants
#define BS    2048            // batch
#define NROW  4096            // B*V = N
#define EDIM  256
#define INVT  (1.0f/0.07f)

typedef float  float4v __attribute__((ext_vector_type(4)));
typedef short  short4v __attribute__((ext_vector_type(4)));
typedef short  short8v __attribute__((ext_vector_type(8)));

static __device__ __forceinline__ unsigned short f2bf(float x) {
    // round-to-nearest-even f32 -> bf16 (inputs are finite)
    unsigned u = __builtin_bit_cast(unsigned, x);
    u += 0x7fffu + ((u >> 16) & 1u);
    return (unsigned short)(u >> 16);
}

static __device__ __forceinline__ void gload_lds16(const void* g, void* l) {
    __builtin_amdgcn_global_load_lds(
        (const __attribute__((address_space(1))) unsigned int*)g,
        (__attribute__((address_space(3))) unsigned int*)l, 16, 0, 0);
}

// ---------------- prep kernel: normalize + label bits + zero accumulators ----
// r12: vectorized + 8x fewer blocks (4104 -> 520).  Main is at its structural
// plateau (r6, 53.5us); the constant ~56us total-main overhead bucket is the
// remaining lever, and prep was 4104 tiny blocks with SCALAR f32 loads
// (Common-mistake #2 / G13).  Now: blocks 0..511 normalize 8 rows each --
// wave w handles row blk*8 + it*4 + w, lane l loads float4 (elems 4l..4l+3,
// all in head l>>4 since head = elem>>6), 16-lane-group shfl reduce
// (offs 1,2,4,8), short4 store.  Same FP sum class, identical f2bf rounding.
// Blocks 512..519: label bits + accumulator zeroing (unchanged logic).
__global__ void prep_kernel(const float* __restrict__ feat, const float* __restrict__ labels,
                            unsigned short* __restrict__ fnb, unsigned* __restrict__ bits,
                            float* __restrict__ zacc) {
    const int blk = blockIdx.x, t = threadIdx.x;
    if (blk < 512) {
        const int lane = t & 63;
        const int wave = t >> 6;
#pragma unroll
        for (int it = 0; it < 2; ++it) {
            const int b  = blk * 8 + it * 4 + wave;   // row 0..4095
            const int bb = b & (BS - 1);
            const int v  = b >> 11;
            float4v x = *(const float4v*)(feat + (size_t)bb * (2 * EDIM)
                                               + (size_t)v * EDIM + lane * 4);
            float ss = x[0]*x[0] + x[1]*x[1] + x[2]*x[2] + x[3]*x[3];
            // reduce over the 16-lane head group (head = lane>>4)
            ss += __shfl_xor(ss, 1, 64);
            ss += __shfl_xor(ss, 2, 64);
            ss += __shfl_xor(ss, 4, 64);
            ss += __shfl_xor(ss, 8, 64);
            const float inv = 1.0f / fmaxf(sqrtf(ss), 1e-12f);
            short4v o;
            o[0] = (short)f2bf(x[0] * inv);
            o[1] = (short)f2bf(x[1] * inv);
            o[2] = (short)f2bf(x[2] * inv);
            o[3] = (short)f2bf(x[3] * inv);
            *(short4v*)(fnb + (size_t)b * EDIM + lane * 4) = o;
        }
    } else {
        int g = (blk - 512) * 256 + t;   // 0..2047
        unsigned bb = 0;
#pragma unroll
        for (int d = 0; d < 10; ++d)
            bb |= (labels[g * 10 + d] != 0.0f ? 1u : 0u) << d;
        bits[g] = bb;
        // zero S (N*4), Num (N), Cnt (N*4), red[2], done[1] = N*9+3 words
        for (int k = g; k < NROW * 9 + 3; k += 2048) zacc[k] = 0.0f;
    }
}

// ---------------- main kernel: r6 VERBATIM (53.5us proven) -------------------
// grid (64 i-tiles, 16 j-chunks) = 1024 blocks, block 256 = 4 waves.
// j-chunk 256 as 8 dbuf 32-row subtiles: STAGE(st+1) before compute(st), one
// barrier/subtile; epilogue interleaved per js-half (dacc[4] live = 16 regs);
// (256,4) -> 4 blocks/CU, all 1024 blocks co-resident, zero tail, no spill.
// Structural exploration CLOSED after r7-r11: symmetric (3 fails), reg-direct
// (starved at 512 blk / serialized at 1024), finer grids (per-block overhead).
// C/D layout (m89/m91): col = lane&15, row = (lane>>4)*4 + reg.
__global__ __launch_bounds__(256, 4) void main_kernel(
    const unsigned short* __restrict__ fnb, const unsigned* __restrict__ bits,
    float* __restrict__ S, float* __restrict__ Num, float* __restrict__ Cnt) {

    __shared__ unsigned short shB[2][32 * 256];   // 2 x 16 KiB, swizzled granules

    const int tid  = threadIdx.x;
    const int lane = tid & 63;
    const int wave = tid >> 6;
    const int quad = lane >> 4;
    const int ml   = lane & 15;
    const int xr   = ml & 7;                   // swizzle XOR for this lane's rows
    const int i0   = blockIdx.x * 64 + wave * 16;
    const int jc0  = blockIdx.y * 256;

    // A fragments: af[h][kk], 8 x short8 = 32 VGPRs (rows i0..i0+15)
    short8v af[4][2];
    {
        const unsigned short* ap = fnb + (size_t)(i0 + ml) * EDIM + quad * 8;
#pragma unroll
        for (int h = 0; h < 4; ++h)
#pragma unroll
            for (int kk = 0; kk < 2; ++kk)
                af[h][kk] = *(const short8v*)(ap + h * 64 + kk * 32);
    }

    unsigned ibr[4];
#pragma unroll
    for (int r = 0; r < 4; ++r)
        ibr[r] = bits[(i0 + quad * 4 + r) & (BS - 1)];

    float    Sp[4][4] = {};
    float    np[4] = {};
    unsigned cpk[4] = {};   // per row: 4 x 8-bit argmax-head counts

    // stage 32 j-rows (16 KiB) of subtile st into shB[buf]
    auto STAGE = [&](int st, int buf) {
#pragma unroll
        for (int q = 0; q < 4; ++q) {
            const int G   = tid + 256 * q;          // LDS 16B-granule index 0..1023
            const int row = G >> 5;                 // 0..31
            const int gg  = (G & 31) ^ (row & 7);   // global granule (pre-swizzled src)
            gload_lds16(fnb + (size_t)(jc0 + st * 32 + row) * EDIM + gg * 8,
                        &shB[buf][G * 8]);
        }
    };

    STAGE(0, 0);
    __syncthreads();                    // drains vmcnt(0): subtile 0 staged

    for (int st = 0; st < 8; ++st) {
        const int cur = st & 1;
        if (st < 7) STAGE(st + 1, cur ^ 1);   // in flight during compute below
        const int j0 = jc0 + st * 32;

#pragma unroll
        for (int js = 0; js < 2; ++js) {
            const unsigned jb = bits[(j0 + js * 16 + ml) & (BS - 1)];

            float4v dacc[4];   // [h] -- live range = this js-half only (16 regs)
#pragma unroll
            for (int h = 0; h < 4; ++h) dacc[h] = (float4v){0.f, 0.f, 0.f, 0.f};
#pragma unroll
            for (int h = 0; h < 4; ++h)
#pragma unroll
                for (int kk = 0; kk < 2; ++kk) {
                    const int gsw = ((h * 8 + kk * 4 + quad) ^ xr) * 8;  // elem offset
                    short8v bf = *(const short8v*)(&shB[cur][(js * 16 + ml) * 256 + gsw]);
                    dacc[h] = __builtin_amdgcn_mfma_f32_16x16x32_bf16(af[h][kk], bf, dacc[h], 0, 0, 0);
                }

            const int j = j0 + js * 16 + ml;
#pragma unroll
            for (int r = 0; r < 4; ++r) {
                const int i = i0 + quad * 4 + r;
                const float d0 = dacc[0][r];
                const float d1 = dacc[1][r];
                const float d2 = dacc[2][r];
                const float d3 = dacc[3][r];
                // argmax, first index wins ties
                float bd = d0; int bh = 0;
                if (d1 > bd) { bd = d1; bh = 1; }
                if (d2 > bd) { bd = d2; bh = 2; }
                if (d3 > bd) { bd = d3; bh = 3; }
                const bool off = (i != j);
                const float e0 = __expf(fmaf(d0, INVT, -INVT));
                const float e1 = __expf(fmaf(d1, INVT, -INVT));
                const float e2 = __expf(fmaf(d2, INVT, -INVT));
                const float e3 = __expf(fmaf(d3, INVT, -INVT));
                if (off) {
                    Sp[r][0] += e0; Sp[r][1] += e1; Sp[r][2] += e2; Sp[r][3] += e3;
                }
                if (off && (ibr[r] & jb)) {
                    np[r] += bd;              // raw dot; * INVT at flush
                    cpk[r] += 1u << (bh * 8);
                }
            }
        }
        __syncthreads();   // all waves done reading shB[cur]; own STAGE(st+1) drained
    }

    // reduce the 16 lanes sharing each row, then one global atomic per value
#pragma unroll
    for (int r = 0; r < 4; ++r) {
        const int i = i0 + quad * 4 + r;
        float v[9];
        v[0] = np[r];
#pragma unroll
        for (int h = 0; h < 4; ++h) v[1 + h] = Sp[r][h];
#pragma unroll
        for (int h = 0; h < 4; ++h) v[5 + h] = (float)((cpk[r] >> (8 * h)) & 255u);
#pragma unroll
        for (int k = 0; k < 9; ++k) {
            float x = v[k];
            x += __shfl_xor(x, 1, 64);
            x += __shfl_xor(x, 2, 64);
            x += __shfl_xor(x, 4, 64);
            x += __shfl_xor(x, 8, 64);
            v[k] = x;
        }
        if (ml == 0) {
            atomicAdd(&Num[i], v[0] * INVT);
#pragma unroll
            for (int h = 0; h < 4; ++h) atomicAdd(&S[i * 4 + h], v[1 + h]);
#pragma unroll
            for (int h = 0; h < 4; ++h) atomicAdd(&Cnt[i * 4 + h], v[5 + h]);
        }
    }
}

// ---------------- final reduction: 16 blocks, last block writes out --------
__global__ void final_kernel(const float* __restrict__ S, const float* __restrict__ Num,
                             const float* __restrict__ Cnt, float* __restrict__ red,
                             unsigned* __restrict__ done, float* __restrict__ out) {
    const int tid = threadIdx.x;
    const int i = blockIdx.x * 256 + tid;   // grid 16 x 256 = 4096 rows exactly
    float c = 0.f;
    float numr = Num[i];
#pragma unroll
    for (int h = 0; h < 4; ++h) {
        float sh = S[i * 4 + h];
        float ch = Cnt[i * 4 + h];
        numr -= ch * (INVT + logf(sh));
        c += ch;
    }
    float ls = 0.f, lc = 0.f;
    if (c > 0.f) { ls = -(numr / c); lc = 1.f; }

    __shared__ float rs[256], rc[256];
    rs[tid] = ls; rc[tid] = lc;
    __syncthreads();
    for (int s = 128; s > 0; s >>= 1) {
        if (tid < s) { rs[tid] += rs[tid + s]; rc[tid] += rc[tid + s]; }
        __syncthreads();
    }
    if (tid == 0) {
        atomicAdd(&red[0], rs[0]);
        atomicAdd(&red[1], rc[0]);
        __threadfence();
        if (atomicAdd(done, 1u) == 15u) {
            float s = atomicAdd(&red[0], 0.0f);
            float cc = atomicAdd(&red[1], 0.0f);
            out[0] = s / cc;
        }
    }
}

extern "C" void kernel_launch(void* const* d_in, const int* in_sizes, int n_in,
                              void* d_out, int out_size, void* d_ws, size_t ws_size,
                              hipStream_t stream) {
    const float* feat = (const float*)d_in[0];    // (2048, 2, 256) f32
    const float* labels = (const float*)d_in[1];  // (2048, 10) f32
    float* out = (float*)d_out;

    char* ws = (char*)d_ws;
    unsigned short* fnb = (unsigned short*)ws;                     // N*E bf16 (2 MB)
    float* S = (float*)(ws + (size_t)NROW * EDIM * sizeof(unsigned short));
    float* Num = S + NROW * 4;
    float* Cnt = Num + NROW;
    float* red = Cnt + NROW * 4;              // red[0]=sum, red[1]=count
    unsigned* done = (unsigned*)(red + 2);    // completion counter
    unsigned* bits = done + 1;                // BS label bitmasks

    prep_kernel<<<520, 256, 0, stream>>>(feat, labels, fnb, bits, S);
    main_kernel<<<dim3(64, 16), 256, 0, stream>>>(fnb, bits, S, Num, Cnt);
    final_kernel<<<16, 256, 0, stream>>>(S, Num, Cnt, red, done, out);
}

// Round 13
// 107.693 us; speedup vs baseline: 1.3624x; 1.0037x over previous
//
#include <hip/hip_runtime.h>
#include <math.h>

// Problem constants
#define BS    2048            // batch
#define NROW  4096            // B*V = N
#define EDIM  256
#define INVT  (1.0f/0.07f)

typedef float  float4v __attribute__((ext_vector_type(4)));
typedef short  short4v __attribute__((ext_vector_type(4)));
typedef short  short8v __attribute__((ext_vector_type(8)));

static __device__ __forceinline__ unsigned short f2bf(float x) {
    // round-to-nearest-even f32 -> bf16 (inputs are finite)
    unsigned u = __builtin_bit_cast(unsigned, x);
    u += 0x7fffu + ((u >> 16) & 1u);
    return (unsigned short)(u >> 16);
}

static __device__ __forceinline__ void gload_lds16(const void* g, void* l) {
    __builtin_amdgcn_global_load_lds(
        (const __attribute__((address_space(1))) unsigned int*)g,
        (__attribute__((address_space(3))) unsigned int*)l, 16, 0, 0);
}

// ---------------- prep kernel (r12, kept): vectorized normalize + bits -------
__global__ void prep_kernel(const float* __restrict__ feat, const float* __restrict__ labels,
                            unsigned short* __restrict__ fnb, unsigned* __restrict__ bits,
                            float* __restrict__ zacc) {
    const int blk = blockIdx.x, t = threadIdx.x;
    if (blk < 512) {
        const int lane = t & 63;
        const int wave = t >> 6;
#pragma unroll
        for (int it = 0; it < 2; ++it) {
            const int b  = blk * 8 + it * 4 + wave;   // row 0..4095
            const int bb = b & (BS - 1);
            const int v  = b >> 11;
            float4v x = *(const float4v*)(feat + (size_t)bb * (2 * EDIM)
                                               + (size_t)v * EDIM + lane * 4);
            float ss = x[0]*x[0] + x[1]*x[1] + x[2]*x[2] + x[3]*x[3];
            ss += __shfl_xor(ss, 1, 64);
            ss += __shfl_xor(ss, 2, 64);
            ss += __shfl_xor(ss, 4, 64);
            ss += __shfl_xor(ss, 8, 64);
            const float inv = 1.0f / fmaxf(sqrtf(ss), 1e-12f);
            short4v o;
            o[0] = (short)f2bf(x[0] * inv);
            o[1] = (short)f2bf(x[1] * inv);
            o[2] = (short)f2bf(x[2] * inv);
            o[3] = (short)f2bf(x[3] * inv);
            *(short4v*)(fnb + (size_t)b * EDIM + lane * 4) = o;
        }
    } else {
        int g = (blk - 512) * 256 + t;   // 0..2047
        unsigned bb = 0;
#pragma unroll
        for (int d = 0; d < 10; ++d)
            bb |= (labels[g * 10 + d] != 0.0f ? 1u : 0u) << d;
        bits[g] = bb;
        // zero S (N*4), Num (N), Cnt (N*4), red[2], done[1] = N*9+3 words
        for (int k = g; k < NROW * 9 + 3; k += 2048) zacc[k] = 0.0f;
    }
}

// ---------------- main kernel: T4 counted-vmcnt, 3-buffer, 2-deep prefetch ---
// r12 post-mortem: main's issue work ~9us vs 52us wall (80% stall, both pipes
// idle).  Remaining structural cause: __syncthreads per subtile = s_waitcnt
// vmcnt(0)+s_barrier, which DRAINS the just-issued STAGE(st+1) prefetch every
// subtile (the m97 barrier-drain stall; T4 counted-vmcnt is the fix, needs
// prefetch depth 2).  This round: 16 subtiles of 16 rows, 3 buffers (24 KiB,
// keeps 4 blocks/CU), STAGE(st+2) issued per iter; loop head does
// s_waitcnt vmcnt(2) (STAGE(st) guaranteed, STAGE(st+1) rides ACROSS the raw
// s_barrier) + sched_barrier(0) (rule #18: pin ds_reads below).
// vmcnt counting is exact because bits[] loads are hoisted to jbr[16] and the
// st loop is FULLY unrolled (rule #20: static jbr index, static buf %3).
// Buffer safety: STAGE(st+2) writes buf[(st-1)%3]; its readers (compute(st-1))
// all crossed barrier(st) beforehand.  WAW: vmcnt(2) retires STAGE(st-1).
// Same j-visit order as r6 -> bit-identical accumulation (absmax 0).
// C/D layout (m89/m91): col = lane&15, row = (lane>>4)*4 + reg.
__global__ __launch_bounds__(256, 4) void main_kernel(
    const unsigned short* __restrict__ fnb, const unsigned* __restrict__ bits,
    float* __restrict__ S, float* __restrict__ Num, float* __restrict__ Cnt) {

    __shared__ unsigned short shB[3][16 * 256];   // 3 x 8 KiB, swizzled granules

    const int tid  = threadIdx.x;
    const int lane = tid & 63;
    const int wave = tid >> 6;
    const int quad = lane >> 4;
    const int ml   = lane & 15;
    const int xr   = ml & 7;                   // swizzle XOR for this lane's rows
    const int i0   = blockIdx.x * 64 + wave * 16;
    const int jc0  = blockIdx.y * 256;

    // A fragments: af[h][kk], 8 x short8 = 32 VGPRs (rows i0..i0+15)
    short8v af[4][2];
    {
        const unsigned short* ap = fnb + (size_t)(i0 + ml) * EDIM + quad * 8;
#pragma unroll
        for (int h = 0; h < 4; ++h)
#pragma unroll
            for (int kk = 0; kk < 2; ++kk)
                af[h][kk] = *(const short8v*)(ap + h * 64 + kk * 32);
    }

    unsigned ibr[4];
#pragma unroll
    for (int r = 0; r < 4; ++r)
        ibr[r] = bits[(i0 + quad * 4 + r) & (BS - 1)];

    // all 16 subtile label-masks hoisted (keeps the loop's vmcnt count exact)
    unsigned jbr[16];
#pragma unroll
    for (int st = 0; st < 16; ++st)
        jbr[st] = bits[(jc0 + st * 16 + ml) & (BS - 1)];

    float    Sp[4][4] = {};
    float    np[4] = {};
    unsigned cpk[4] = {};   // per row: 4 x 8-bit argmax-head counts (<=16/lane)

    // stage 16 j-rows (8 KiB) of subtile st into shB[buf]; 2 loads/thread
    auto STAGE = [&](int st, int buf) {
#pragma unroll
        for (int q = 0; q < 2; ++q) {
            const int G   = tid + 256 * q;          // LDS 16B-granule index 0..511
            const int row = G >> 5;                 // 0..15
            const int gg  = (G & 31) ^ (row & 7);   // global granule (pre-swizzled src)
            gload_lds16(fnb + (size_t)(jc0 + st * 16 + row) * EDIM + gg * 8,
                        &shB[buf][G * 8]);
        }
    };

    STAGE(0, 0);
    STAGE(1, 1);

#pragma unroll
    for (int st = 0; st < 16; ++st) {
        // counted wait: everything except the newest 2 VMEM ops (= STAGE(st+1))
        // must be complete -> STAGE(st) landed; STAGE(st+1) stays in flight
        // across the barrier (T4).  Last iter has nothing newer: drain.
        if (st < 15) asm volatile("s_waitcnt vmcnt(2)" ::: "memory");
        else         asm volatile("s_waitcnt vmcnt(0)" ::: "memory");
        __builtin_amdgcn_s_barrier();
        __builtin_amdgcn_sched_barrier(0);      // rule #18: no hoist above wait

        const int cur = st % 3;                 // static after full unroll
        const int j0  = jc0 + st * 16;
        const unsigned jb = jbr[st];

        float4v dacc[4];   // [h] -- live range = this subtile only (16 regs)
#pragma unroll
        for (int h = 0; h < 4; ++h) dacc[h] = (float4v){0.f, 0.f, 0.f, 0.f};
#pragma unroll
        for (int h = 0; h < 4; ++h)
#pragma unroll
            for (int kk = 0; kk < 2; ++kk) {
                const int gsw = ((h * 8 + kk * 4 + quad) ^ xr) * 8;  // elem offset
                short8v bf = *(const short8v*)(&shB[cur][ml * 256 + gsw]);
                dacc[h] = __builtin_amdgcn_mfma_f32_16x16x32_bf16(af[h][kk], bf, dacc[h], 0, 0, 0);
            }

        const int j = j0 + ml;
#pragma unroll
        for (int r = 0; r < 4; ++r) {
            const int i = i0 + quad * 4 + r;
            const float d0 = dacc[0][r];
            const float d1 = dacc[1][r];
            const float d2 = dacc[2][r];
            const float d3 = dacc[3][r];
            // argmax, first index wins ties
            float bd = d0; int bh = 0;
            if (d1 > bd) { bd = d1; bh = 1; }
            if (d2 > bd) { bd = d2; bh = 2; }
            if (d3 > bd) { bd = d3; bh = 3; }
            const bool off = (i != j);
            const float e0 = __expf(fmaf(d0, INVT, -INVT));
            const float e1 = __expf(fmaf(d1, INVT, -INVT));
            const float e2 = __expf(fmaf(d2, INVT, -INVT));
            const float e3 = __expf(fmaf(d3, INVT, -INVT));
            if (off) {
                Sp[r][0] += e0; Sp[r][1] += e1; Sp[r][2] += e2; Sp[r][3] += e3;
            }
            if (off && (ibr[r] & jb)) {
                np[r] += bd;              // raw dot; * INVT at flush
                cpk[r] += 1u << (bh * 8);
            }
        }

        if (st + 2 < 16) STAGE(st + 2, (st + 2) % 3);
    }

    // reduce the 16 lanes sharing each row, then one global atomic per value
#pragma unroll
    for (int r = 0; r < 4; ++r) {
        const int i = i0 + quad * 4 + r;
        float v[9];
        v[0] = np[r];
#pragma unroll
        for (int h = 0; h < 4; ++h) v[1 + h] = Sp[r][h];
#pragma unroll
        for (int h = 0; h < 4; ++h) v[5 + h] = (float)((cpk[r] >> (8 * h)) & 255u);
#pragma unroll
        for (int k = 0; k < 9; ++k) {
            float x = v[k];
            x += __shfl_xor(x, 1, 64);
            x += __shfl_xor(x, 2, 64);
            x += __shfl_xor(x, 4, 64);
            x += __shfl_xor(x, 8, 64);
            v[k] = x;
        }
        if (ml == 0) {
            atomicAdd(&Num[i], v[0] * INVT);
#pragma unroll
            for (int h = 0; h < 4; ++h) atomicAdd(&S[i * 4 + h], v[1 + h]);
#pragma unroll
            for (int h = 0; h < 4; ++h) atomicAdd(&Cnt[i * 4 + h], v[5 + h]);
        }
    }
}

// ---------------- final reduction: 16 blocks, last block writes out --------
__global__ void final_kernel(const float* __restrict__ S, const float* __restrict__ Num,
                             const float* __restrict__ Cnt, float* __restrict__ red,
                             unsigned* __restrict__ done, float* __restrict__ out) {
    const int tid = threadIdx.x;
    const int i = blockIdx.x * 256 + tid;   // grid 16 x 256 = 4096 rows exactly
    float c = 0.f;
    float numr = Num[i];
#pragma unroll
    for (int h = 0; h < 4; ++h) {
        float sh = S[i * 4 + h];
        float ch = Cnt[i * 4 + h];
        numr -= ch * (INVT + logf(sh));
        c += ch;
    }
    float ls = 0.f, lc = 0.f;
    if (c > 0.f) { ls = -(numr / c); lc = 1.f; }

    __shared__ float rs[256], rc[256];
    rs[tid] = ls; rc[tid] = lc;
    __syncthreads();
    for (int s = 128; s > 0; s >>= 1) {
        if (tid < s) { rs[tid] += rs[tid + s]; rc[tid] += rc[tid + s]; }
        __syncthreads();
    }
    if (tid == 0) {
        atomicAdd(&red[0], rs[0]);
        atomicAdd(&red[1], rc[0]);
        __threadfence();
        if (atomicAdd(done, 1u) == 15u) {
            float s = atomicAdd(&red[0], 0.0f);
            float cc = atomicAdd(&red[1], 0.0f);
            out[0] = s / cc;
        }
    }
}

extern "C" void kernel_launch(void* const* d_in, const int* in_sizes, int n_in,
                              void* d_out, int out_size, void* d_ws, size_t ws_size,
                              hipStream_t stream) {
    const float* feat = (const float*)d_in[0];    // (2048, 2, 256) f32
    const float* labels = (const float*)d_in[1];  // (2048, 10) f32
    float* out = (float*)d_out;

    char* ws = (char*)d_ws;
    unsigned short* fnb = (unsigned short*)ws;                     // N*E bf16 (2 MB)
    float* S = (float*)(ws + (size_t)NROW * EDIM * sizeof(unsigned short));
    float* Num = S + NROW * 4;
    float* Cnt = Num + NROW;
    float* red = Cnt + NROW * 4;              // red[0]=sum, red[1]=count
    unsigned* done = (unsigned*)(red + 2);    // completion counter
    unsigned* bits = done + 1;                // BS label bitmasks

    prep_kernel<<<520, 256, 0, stream>>>(feat, labels, fnb, bits, S);
    main_kernel<<<dim3(64, 16), 256, 0, stream>>>(fnb, bits, S, Num, Cnt);
    final_kernel<<<16, 256, 0, stream>>>(S, Num, Cnt, red, done, out);
}